// Round 4
// baseline (259.273 us; speedup 1.0000x reference)
//
#include <hip/hip_runtime.h>
#include <math.h>

#define BB 64
#define LL 512
#define SS 512
#define HH 768
#define CC 9
#define WPV 4                       // words per wave
#define WPB (WPV * 4)               // 16 words per block (4 waves)
#define GW (BB * SS / WPB)          // 2048 blocks
#define NPART (GW * 4)              // 8192 per-wave partials

// DPP full-wave (64-lane) sum; total lands in lane 63. Pure VALU, no LDS.
template <int CTRL>
__device__ __forceinline__ float dpp_add(float x) {
    int y = __builtin_amdgcn_update_dpp(0, __float_as_int(x), CTRL, 0xf, 0xf, true);
    return x + __int_as_float(y);
}
__device__ __forceinline__ float rsum64(float x) {
    x = dpp_add<0x111>(x);  // row_shr:1
    x = dpp_add<0x112>(x);  // row_shr:2
    x = dpp_add<0x114>(x);  // row_shr:4
    x = dpp_add<0x118>(x);  // row_shr:8
    x = dpp_add<0x142>(x);  // row_bcast:15
    x = dpp_add<0x143>(x);  // row_bcast:31 -> lane 63 = full sum
    return x;
}

__device__ __forceinline__ float4 f4add(float4 a, float4 b) {
    return make_float4(a.x + b.x, a.y + b.y, a.z + b.z, a.w + b.w);
}
__device__ __forceinline__ float dot4(float4 a, float4 b) {
    return a.x * b.x + a.y * b.y + a.z * b.z + a.w * b.w;
}

// Kernel 0: blocks 0..63 = per-batch exclusive scan of ids_lens -> woff;
//           block 64     = W[H][C] -> WT[C][H] transpose.
__global__ __launch_bounds__(512) void scan_wt_kernel(
    const int* __restrict__ ids_lens,   // [B, S]
    const float* __restrict__ Wm,       // [H, C]
    int* __restrict__ woff_g,           // [B, S] start row of each word
    float* __restrict__ WT_g)           // [C, H]
{
    if (blockIdx.x == BB) {
        for (int e = threadIdx.x; e < HH * CC; e += 512) {
            int h = e / CC;
            int c = e - h * CC;
            WT_g[c * HH + h] = Wm[e];
        }
        return;
    }
    __shared__ int wtot[8];
    int b = blockIdx.x;
    int t = threadIdx.x, lane = t & 63, wave = t >> 6;
    int len = ids_lens[b * SS + t];
    int x = len;                         // wave-level inclusive scan (exact int)
#pragma unroll
    for (int off = 1; off < 64; off <<= 1) {
        int y = __shfl_up(x, off);
        if (lane >= off) x += y;
    }
    if (lane == 63) wtot[wave] = x;
    __syncthreads();
    int base = 0;
    for (int wv = 0; wv < wave; wv++) base += wtot[wv];
    woff_g[b * SS + t] = base + x - len; // exclusive scan = start row
}

// Kernel 1: word hot kernel. NO LDS, NO barriers. Wave owns 4 words.
// H split into 3 passes of 256 floats so each pass's working set
// (9 W float4 + 12 bert float4 + 4 pools + 36 acc) fits in registers and
// ALL 21 loads of a pass issue back-to-back (full memory parallelism).
__global__ __launch_bounds__(256, 3) void word_kernel(
    const float* __restrict__ bert,      // [B*L, H]
    const float* __restrict__ WT_g,      // [C][H]
    const float* __restrict__ bias,      // [C]
    const int* __restrict__ ids_lens,    // [B*S]
    const int* __restrict__ woff_g,      // [B*S]
    const int* __restrict__ label_ids,   // [B*S]
    float* __restrict__ pred_out,        // d_out + 1
    float* __restrict__ nll_part,        // [NPART]
    float* __restrict__ cnt_part)        // [NPART]
{
    int t = threadIdx.x, lane = t & 63, wave = t >> 6;
    int hoff = lane * 4;
    int g0 = blockIdx.x * WPB + wave * WPV;  // wave's 4 consecutive words
    int pid = blockIdx.x * 4 + wave;

    // lens as wave-uniform SGPRs: scalar branches + SGPR addressing
    int len[WPV];
#pragma unroll
    for (int i = 0; i < WPV; i++)
        len[i] = __builtin_amdgcn_readfirstlane(ids_lens[g0 + i]);

    if ((len[0] | len[1] | len[2] | len[3]) == 0) {   // all 4 words empty
        if (lane == 63) {
            float mx = bias[0]; int arg = 0;
#pragma unroll
            for (int c = 1; c < CC; c++) { float v = bias[c]; if (v > mx) { mx = v; arg = c; } }
#pragma unroll
            for (int i = 0; i < WPV; i++) pred_out[g0 + i] = (float)arg;
            nll_part[pid] = 0.0f;
            cnt_part[pid] = 0.0f;
        }
        return;
    }

    int off[WPV];
#pragma unroll
    for (int i = 0; i < WPV; i++)
        off[i] = __builtin_amdgcn_readfirstlane(woff_g[g0 + i]);

    int b = g0 >> 9;                      // 512 words per batch; WPB | 512
    const float* rowbase = bert + (size_t)b * LL * HH + hoff;

    float acc[CC][WPV];
#pragma unroll
    for (int c = 0; c < CC; c++)
#pragma unroll
        for (int i = 0; i < WPV; i++) acc[c][i] = 0.0f;

#pragma unroll
    for (int p = 0; p < 3; p++) {
        // W chunk first (independent of bert loads -> issues immediately)
        float4 w[CC];
#pragma unroll
        for (int c = 0; c < CC; c++)
            w[c] = *reinterpret_cast<const float4*>(WT_g + c * HH + p * 256 + hoff);

        // all bert row-chunk loads of this pass (<=12, batched)
        float4 r0[WPV], r1[WPV], r2[WPV];
#pragma unroll
        for (int i = 0; i < WPV; i++) {
            const float* q = rowbase + (size_t)off[i] * HH + p * 256;
            if (len[i] > 0) r0[i] = *reinterpret_cast<const float4*>(q);
            if (len[i] > 1) r1[i] = *reinterpret_cast<const float4*>(q + HH);
            if (len[i] > 2) r2[i] = *reinterpret_cast<const float4*>(q + 2 * HH);
        }

        // pool + dot-accumulate
#pragma unroll
        for (int i = 0; i < WPV; i++) {
            float4 s = make_float4(0.f, 0.f, 0.f, 0.f);
            if (len[i] > 0) s = r0[i];
            if (len[i] > 1) s = f4add(s, r1[i]);
            if (len[i] > 2) s = f4add(s, r2[i]);
#pragma unroll
            for (int c = 0; c < CC; c++) acc[c][i] += dot4(s, w[c]);
        }
    }

    // 36 independent 6-step DPP chains (good ILP)
#pragma unroll
    for (int c = 0; c < CC; c++)
#pragma unroll
        for (int i = 0; i < WPV; i++) acc[c][i] = rsum64(acc[c][i]);

    if (lane == 63) {
        float bs[CC];
#pragma unroll
        for (int c = 0; c < CC; c++) bs[c] = bias[c];
        float nll = 0.0f, cnt = 0.0f;
#pragma unroll
        for (int i = 0; i < WPV; i++) {
            int ln = len[i];
            float inv = (ln > 0) ? (1.0f / (float)ln) : 1.0f;
            float lg[CC];
#pragma unroll
            for (int c = 0; c < CC; c++) lg[c] = acc[c][i] * inv + bs[c];
            float mx = lg[0]; int arg = 0;
#pragma unroll
            for (int c = 1; c < CC; c++) { if (lg[c] > mx) { mx = lg[c]; arg = c; } }
            float se = 0.0f;
#pragma unroll
            for (int c = 0; c < CC; c++) se += expf(lg[c] - mx);
            float lse = mx + logf(se);
            int g = g0 + i;
            int lab = label_ids[g];
            lab = lab < 0 ? 0 : (lab > CC - 1 ? CC - 1 : lab);
            if (ln > 0) { nll += lse - lg[lab]; cnt += 1.0f; }
            pred_out[g] = (float)arg;
        }
        nll_part[pid] = nll;
        cnt_part[pid] = cnt;
    }
}

// Kernel 2: deterministic reduction of 8192 per-wave partials -> loss
__global__ __launch_bounds__(1024) void finalize_kernel(
    const float* __restrict__ nll_part,
    const float* __restrict__ cnt_part,
    float* __restrict__ out_loss) {
    __shared__ float sn[16], sc[16];
    int t = threadIdx.x, lane = t & 63, wave = t >> 6;
    float n = 0.0f, c = 0.0f;
#pragma unroll
    for (int i = 0; i < NPART / 1024; ++i) {
        n += nll_part[t + i * 1024];
        c += cnt_part[t + i * 1024];
    }
    n = rsum64(n);
    c = rsum64(c);
    if (lane == 63) { sn[wave] = n; sc[wave] = c; }
    __syncthreads();
    if (t == 0) {
        float tn = 0.0f, tc = 0.0f;
#pragma unroll
        for (int i = 0; i < 16; i++) { tn += sn[i]; tc += sc[i]; }
        out_loss[0] = tn / fmaxf(tc, 1.0f);
    }
}

extern "C" void kernel_launch(void* const* d_in, const int* in_sizes, int n_in,
                              void* d_out, int out_size, void* d_ws, size_t ws_size,
                              hipStream_t stream) {
    const float* bert = (const float*)d_in[0]; // float32 [B,L,H]
    const float* Wm   = (const float*)d_in[1]; // float32 [H,C]
    const float* bias = (const float*)d_in[2]; // float32 [C]
    // d_in[3] = attention_mask (unused: prefix mask implied by ids_lens)
    const int* ids_lens  = (const int*)d_in[4];
    const int* label_ids = (const int*)d_in[5];
    // d_in[6] = label_mask (derived from ids_lens > 0)

    float* out = (float*)d_out;  // [0]=loss, [1..32768]=pred, float32

    float* WT_g     = (float*)d_ws;                    // [C][H]  27648 B
    int*   woff_g   = (int*)(WT_g + CC * HH);          // [B*S]   128 KB
    float* nll_part = (float*)(woff_g + BB * SS);      // [NPART]
    float* cnt_part = nll_part + NPART;                // [NPART]

    scan_wt_kernel<<<BB + 1, 512, 0, stream>>>(ids_lens, Wm, woff_g, WT_g);
    word_kernel<<<GW, 256, 0, stream>>>(bert, WT_g, bias, ids_lens, woff_g,
                                        label_ids, out + 1, nll_part, cnt_part);
    finalize_kernel<<<1, 1024, 0, stream>>>(nll_part, cnt_part, out);
}

// Round 5
// 183.201 us; speedup vs baseline: 1.4152x; 1.4152x over previous
//
#include <hip/hip_runtime.h>
#include <math.h>

#define BB 64
#define LL 512
#define SS 512
#define HH 768
#define CC 9
#define NROWS (BB * LL)            // 32768 subword rows
#define RLW 12                     // RL row stride in floats (9 + 3 pad)
#define RPV 4                      // rows per wave in logit_kernel
#define G1 (NROWS / (RPV * 4))     // 2048 blocks
#define NWORDS (BB * SS)           // 32768 words
#define G2 (NWORDS / 256)          // 128 pool blocks (1 word per lane)
#define NPART (G2 * 4)             // 512 per-wave partials

// DPP full-wave (64-lane) sum; total lands in lane 63. Pure VALU, no LDS.
template <int CTRL>
__device__ __forceinline__ float dpp_add(float x) {
    int y = __builtin_amdgcn_update_dpp(0, __float_as_int(x), CTRL, 0xf, 0xf, true);
    return x + __int_as_float(y);
}
__device__ __forceinline__ float rsum64(float x) {
    x = dpp_add<0x111>(x);  // row_shr:1
    x = dpp_add<0x112>(x);  // row_shr:2
    x = dpp_add<0x114>(x);  // row_shr:4
    x = dpp_add<0x118>(x);  // row_shr:8
    x = dpp_add<0x142>(x);  // row_bcast:15
    x = dpp_add<0x143>(x);  // row_bcast:31 -> lane 63 = full sum
    return x;
}

__device__ __forceinline__ float4 f4add(float4 a, float4 b) {
    return make_float4(a.x + b.x, a.y + b.y, a.z + b.z, a.w + b.w);
}
__device__ __forceinline__ float dot4(float4 a, float4 b) {
    return a.x * b.x + a.y * b.y + a.z * b.z + a.w * b.w;
}

// Kernel 0: blocks 0..63 = per-batch exclusive scan of ids_lens -> woff;
//           block 64     = W[H][C] -> WT[C][H] transpose.
__global__ __launch_bounds__(512) void scan_wt_kernel(
    const int* __restrict__ ids_lens,   // [B, S]
    const float* __restrict__ Wm,       // [H, C]
    int* __restrict__ woff_g,           // [B, S] start row of each word
    float* __restrict__ WT_g)           // [C, H]
{
    if (blockIdx.x == BB) {
        for (int e = threadIdx.x; e < HH * CC; e += 512) {
            int h = e / CC;
            int c = e - h * CC;
            WT_g[c * HH + h] = Wm[e];
        }
        return;
    }
    __shared__ int wtot[8];
    int b = blockIdx.x;
    int t = threadIdx.x, lane = t & 63, wave = t >> 6;
    int len = ids_lens[b * SS + t];
    int x = len;                         // wave-level inclusive scan (exact int)
#pragma unroll
    for (int off = 1; off < 64; off <<= 1) {
        int y = __shfl_up(x, off);
        if (lane >= off) x += y;
    }
    if (lane == 63) wtot[wave] = x;
    __syncthreads();
    int base = 0;
    for (int wv = 0; wv < wave; wv++) base += wtot[wv];
    woff_g[b * SS + t] = base + x - len; // exclusive scan = start row
}

// Kernel 1: branch-free row-logit streamer. Wave owns 4 consecutive rows;
// 3 H-chunk iterations, each issuing 13 independent loads (9 WT + 4 bert).
// Live set ~105 VGPRs, no conditionals, no data-dependent addressing.
__global__ __launch_bounds__(256, 4) void logit_kernel(
    const float* __restrict__ bert,      // [B*L, H]
    const float* __restrict__ WT_g,      // [C][H]
    float* __restrict__ RL)              // [NROWS+4][RLW]
{
    int t = threadIdx.x, lane = t & 63, wave = t >> 6;
    int w = blockIdx.x * 4 + wave;       // 0..8191
    size_t row0 = (size_t)w * RPV;
    int hoff = lane * 4;

    float acc[RPV][CC];
#pragma unroll
    for (int r = 0; r < RPV; r++)
#pragma unroll
        for (int c = 0; c < CC; c++) acc[r][c] = 0.0f;

#pragma unroll
    for (int ck = 0; ck < 3; ck++) {
        const float* wp = WT_g + ck * 256 + hoff;
        float4 wv[CC];
#pragma unroll
        for (int c = 0; c < CC; c++)
            wv[c] = *reinterpret_cast<const float4*>(wp + c * HH);

        const float* bp = bert + row0 * HH + ck * 256 + hoff;
        float4 rv[RPV];
#pragma unroll
        for (int r = 0; r < RPV; r++)
            rv[r] = *reinterpret_cast<const float4*>(bp + (size_t)r * HH);

#pragma unroll
        for (int r = 0; r < RPV; r++)
#pragma unroll
            for (int c = 0; c < CC; c++)
                acc[r][c] += dot4(rv[r], wv[c]);
    }

    // 36 independent 6-step DPP chains
#pragma unroll
    for (int r = 0; r < RPV; r++)
#pragma unroll
        for (int c = 0; c < CC; c++)
            acc[r][c] = rsum64(acc[r][c]);

    if (lane == 63) {
#pragma unroll
        for (int r = 0; r < RPV; r++) {
            float* dst = RL + (row0 + r) * RLW;
            *reinterpret_cast<float4*>(dst) =
                make_float4(acc[r][0], acc[r][1], acc[r][2], acc[r][3]);
            *reinterpret_cast<float4*>(dst + 4) =
                make_float4(acc[r][4], acc[r][5], acc[r][6], acc[r][7]);
            *reinterpret_cast<float4*>(dst + 8) =
                make_float4(acc[r][8], 0.0f, 0.0f, 0.0f);   // pads = 0
        }
    }
}

// Kernel 2: ONE WORD PER LANE. Gather <=3 rows x 3 float4 from L2-hot RL,
// mean+bias, softmax/NLL/argmax per lane (no cross-lane reduce for logits),
// coalesced pred writes; one rsum64 per wave for loss partials.
__global__ __launch_bounds__(256) void pool_kernel(
    const float* __restrict__ RL,        // [NROWS+4][RLW]
    const float* __restrict__ bias,      // [C]
    const int* __restrict__ ids_lens,    // [B*S]
    const int* __restrict__ woff_g,      // [B*S]
    const int* __restrict__ label_ids,   // [B*S]
    float* __restrict__ pred_out,        // d_out + 1
    float* __restrict__ nll_part,        // [NPART]
    float* __restrict__ cnt_part)        // [NPART]
{
    int t = threadIdx.x, lane = t & 63, wave = t >> 6;
    int g = blockIdx.x * 256 + t;        // word id, coalesced
    int b = g >> 9;                      // batch (512 words/batch)
    int len = ids_lens[g];
    int off = woff_g[g];
    int lab = label_ids[g];

    size_t row = (size_t)b * LL + off;   // <= 32768+2 reachable; RL has spares
    float4 sA = make_float4(0.f, 0.f, 0.f, 0.f), sB = sA, sC = sA;
#pragma unroll
    for (int j = 0; j < 3; j++) {
        const float* p = RL + (row + j) * RLW;
        float4 A  = *reinterpret_cast<const float4*>(p);
        float4 Bv = *reinterpret_cast<const float4*>(p + 4);
        float4 Cv = *reinterpret_cast<const float4*>(p + 8);
        bool use = j < len;              // select, never multiply: poison-safe
        sA = use ? f4add(sA, A)  : sA;
        sB = use ? f4add(sB, Bv) : sB;
        sC = use ? f4add(sC, Cv) : sC;
    }

    float inv = (len > 0) ? (1.0f / (float)len) : 1.0f;
    float lg[CC];
    lg[0] = sA.x * inv + bias[0];
    lg[1] = sA.y * inv + bias[1];
    lg[2] = sA.z * inv + bias[2];
    lg[3] = sA.w * inv + bias[3];
    lg[4] = sB.x * inv + bias[4];
    lg[5] = sB.y * inv + bias[5];
    lg[6] = sB.z * inv + bias[6];
    lg[7] = sB.w * inv + bias[7];
    lg[8] = sC.x * inv + bias[8];

    float mx = lg[0];
    int arg = 0;
#pragma unroll
    for (int c = 1; c < CC; c++) {
        if (lg[c] > mx) { mx = lg[c]; arg = c; }
    }
    float se = 0.0f;
#pragma unroll
    for (int c = 0; c < CC; c++) se += expf(lg[c] - mx);
    float lse = mx + logf(se);

    lab = lab < 0 ? 0 : (lab > CC - 1 ? CC - 1 : lab);
    float valid = (len > 0) ? 1.0f : 0.0f;
    float nll = (lse - lg[lab]) * valid;

    pred_out[g] = (float)arg;            // coalesced

    float rn = rsum64(nll);
    float rc = rsum64(valid);
    if (lane == 63) {
        nll_part[blockIdx.x * 4 + wave] = rn;
        cnt_part[blockIdx.x * 4 + wave] = rc;
    }
}

// Kernel 3: deterministic reduction of 512 per-wave partials -> loss
__global__ __launch_bounds__(512) void finalize_kernel(
    const float* __restrict__ nll_part,
    const float* __restrict__ cnt_part,
    float* __restrict__ out_loss) {
    __shared__ float sn[8], sc[8];
    int t = threadIdx.x, lane = t & 63, wave = t >> 6;
    float n = rsum64(nll_part[t]);
    float c = rsum64(cnt_part[t]);
    if (lane == 63) { sn[wave] = n; sc[wave] = c; }
    __syncthreads();
    if (t == 0) {
        float tn = 0.0f, tc = 0.0f;
#pragma unroll
        for (int i = 0; i < 8; i++) { tn += sn[i]; tc += sc[i]; }
        out_loss[0] = tn / fmaxf(tc, 1.0f);
    }
}

extern "C" void kernel_launch(void* const* d_in, const int* in_sizes, int n_in,
                              void* d_out, int out_size, void* d_ws, size_t ws_size,
                              hipStream_t stream) {
    const float* bert = (const float*)d_in[0]; // float32 [B,L,H]
    const float* Wm   = (const float*)d_in[1]; // float32 [H,C]
    const float* bias = (const float*)d_in[2]; // float32 [C]
    // d_in[3] = attention_mask (unused: prefix mask implied by ids_lens)
    const int* ids_lens  = (const int*)d_in[4];
    const int* label_ids = (const int*)d_in[5];
    // d_in[6] = label_mask (derived from ids_lens > 0)

    float* out = (float*)d_out;  // [0]=loss, [1..32768]=pred, float32

    float* WT_g     = (float*)d_ws;                       // [C][H]   27648 B
    int*   woff_g   = (int*)(WT_g + CC * HH);             // [B*S]    128 KB
    float* RL       = (float*)(woff_g + NWORDS);          // [NROWS+4][RLW] ~1.6 MB
    float* nll_part = RL + (size_t)(NROWS + 4) * RLW;     // [NPART]
    float* cnt_part = nll_part + NPART;                   // [NPART]

    scan_wt_kernel<<<BB + 1, 512, 0, stream>>>(ids_lens, Wm, woff_g, WT_g);
    logit_kernel<<<G1, 256, 0, stream>>>(bert, WT_g, RL);
    pool_kernel<<<G2, 256, 0, stream>>>(RL, bias, ids_lens, woff_g, label_ids,
                                        out + 1, nll_part, cnt_part);
    finalize_kernel<<<1, 512, 0, stream>>>(nll_part, cnt_part, out);
}

// Round 6
// 179.229 us; speedup vs baseline: 1.4466x; 1.0222x over previous
//
#include <hip/hip_runtime.h>

#define BB 64
#define LL 512
#define SS 512
#define HH 768
#define CC 9
#define NROWS (BB * LL)               // 32768 subword rows
#define RLS 12                        // row-logit stride (floats)
#define G1 1024                       // row_gemm blocks
#define ROWS_PER_BLOCK 32             // 4 waves x 8 rows
#define WPS 64                        // words per pool slice
#define G2 (BB * SS / WPS)            // 512 pool blocks

// DPP full-wave (64-lane) sum; total lands in lane 63. Pure VALU, no LDS.
template <int CTRL>
__device__ __forceinline__ float dpp_add(float x) {
    int y = __builtin_amdgcn_update_dpp(0, __float_as_int(x), CTRL, 0xf, 0xf, true);
    return x + __int_as_float(y);
}
__device__ __forceinline__ float rsum64(float x) {
    x = dpp_add<0x111>(x);  // row_shr:1
    x = dpp_add<0x112>(x);  // row_shr:2
    x = dpp_add<0x114>(x);  // row_shr:4
    x = dpp_add<0x118>(x);  // row_shr:8
    x = dpp_add<0x142>(x);  // row_bcast:15
    x = dpp_add<0x143>(x);  // row_bcast:31 -> lane 63 = full sum
    return x;
}

// Kernel 0: W[H][C] -> WT[C][H] in ws (27 KB, L2-resident after) + zero the
// done-counter used by pool's folded finalize (ws is poisoned every iter).
__global__ __launch_bounds__(256) void wt_kernel(const float* __restrict__ Wm,
                                                 float* __restrict__ WT_g,
                                                 unsigned int* __restrict__ done) {
    if (blockIdx.x == 0 && threadIdx.x == 0) *done = 0u;
    int e = blockIdx.x * 256 + threadIdx.x;   // coalesced read of Wm
    if (e < HH * CC) {
        int h = e / CC;
        int c = e - h * CC;
        WT_g[c * HH + h] = Wm[e];
    }
}

// Kernel 1: streaming per-subword-row logits. No LDS, no barriers.
// Each lane's W slice (27 float4) loaded coalesced from global WT (L2-hot).
__global__ __launch_bounds__(256) void row_gemm_kernel(
    const float* __restrict__ bert,   // [B*L, H]
    const float* __restrict__ WT_g,   // [C][H]
    float* __restrict__ RL)           // [NROWS, RLS] ws
{
    int wave = threadIdx.x >> 6;
    int lane = threadIdx.x & 63;
    int hoff = lane * 4;

    float4 wreg[CC][3];
#pragma unroll
    for (int c = 0; c < CC; c++)
#pragma unroll
        for (int c3 = 0; c3 < 3; c3++)
            wreg[c][c3] = *reinterpret_cast<const float4*>(WT_g + c * HH + c3 * 256 + hoff);

    size_t row0 = (size_t)blockIdx.x * ROWS_PER_BLOCK + wave * 8;

#pragma unroll
    for (int r = 0; r < 8; ++r) {
        const float* p = bert + (row0 + r) * HH + hoff;
        float4 f0 = *reinterpret_cast<const float4*>(p);
        float4 f1 = *reinterpret_cast<const float4*>(p + 256);
        float4 f2 = *reinterpret_cast<const float4*>(p + 512);

        float acc[CC];
#pragma unroll
        for (int c = 0; c < CC; c++) {
            acc[c] = f0.x * wreg[c][0].x + f0.y * wreg[c][0].y
                   + f0.z * wreg[c][0].z + f0.w * wreg[c][0].w
                   + f1.x * wreg[c][1].x + f1.y * wreg[c][1].y
                   + f1.z * wreg[c][1].z + f1.w * wreg[c][1].w
                   + f2.x * wreg[c][2].x + f2.y * wreg[c][2].y
                   + f2.z * wreg[c][2].z + f2.w * wreg[c][2].w;
        }
#pragma unroll
        for (int c = 0; c < CC; c++) acc[c] = rsum64(acc[c]);

        if (lane == 63) {
            float* dst = RL + (row0 + r) * RLS;
            float4 s0; s0.x = acc[0]; s0.y = acc[1]; s0.z = acc[2]; s0.w = acc[3];
            float4 s1; s1.x = acc[4]; s1.y = acc[5]; s1.z = acc[6]; s1.w = acc[7];
            *reinterpret_cast<float4*>(dst) = s0;
            *reinterpret_cast<float4*>(dst + 4) = s1;
            dst[8] = acc[8];
        }
    }
}

// Kernel 2: 512 blocks, each owns 64 words of one batch: slice offset +
// mini-scan + pool + softmax/NLL/argmax + per-block partial. The LAST block
// to finish (device-scope counter) reduces all partials -> loss (folded
// finalize: saves one kernel launch).
__global__ __launch_bounds__(256) void pool_kernel(
    const float* __restrict__ RL,       // [NROWS, RLS]
    const float* __restrict__ bias,     // [C]
    const int* __restrict__ ids_lens,   // [B, S]
    const int* __restrict__ label_ids,  // [B, S]
    float* __restrict__ pred_out,       // d_out + 1
    float* __restrict__ nll_part,       // [G2]
    float* __restrict__ cnt_part,       // [G2]
    unsigned int* __restrict__ done,    // [1], zeroed by wt_kernel
    float* __restrict__ out_loss)       // d_out + 0
{
    __shared__ int wlen[WPS], woff[WPS];
    __shared__ float red[4];
    __shared__ int s_start;
    __shared__ int lastflag;

    int b = blockIdx.x >> 3;            // batch
    int s8 = blockIdx.x & 7;            // slice in batch
    int w0 = s8 * WPS;                  // first word of slice
    const int* lens = ids_lens + b * SS;

    int t = threadIdx.x, lane = t & 63, wave = t >> 6;

    if (t < WPS) wlen[t] = lens[w0 + t];

    // sum of lens[0..w0) -> slice's first subword row
    int part = 0;
    for (int i = t; i < w0; i += 256) part += lens[i];
    float pf = rsum64((float)part);     // integers < 1536: exact
    if (lane == 63) red[wave] = pf;
    __syncthreads();
    if (t == 0) {
        int run = 0;
#pragma unroll
        for (int k = 0; k < WPS; k++) { woff[k] = run; run += wlen[k]; }
        s_start = (int)(red[0] + red[1] + red[2] + red[3]);
    }
    __syncthreads();

    if (t < 64) {
        int k = t;
        int len = wlen[k];
        int off = s_start + woff[k];
        const float* base = RL + ((size_t)b * LL + off) * RLS;

        float s[CC];
#pragma unroll
        for (int c = 0; c < CC; c++) s[c] = 0.0f;
        for (int j = 0; j < len; ++j) {
            const float* p = base + j * RLS;
            float4 a = *reinterpret_cast<const float4*>(p);
            float4 c4 = *reinterpret_cast<const float4*>(p + 4);
            s[0] += a.x;  s[1] += a.y;  s[2] += a.z;  s[3] += a.w;
            s[4] += c4.x; s[5] += c4.y; s[6] += c4.z; s[7] += c4.w;
            s[8] += p[8];
        }
        float inv = 1.0f / (float)(len > 0 ? len : 1);
        float lg[CC];
#pragma unroll
        for (int c = 0; c < CC; c++) lg[c] = s[c] * inv + bias[c];

        float mx = lg[0];
        int arg = 0;
#pragma unroll
        for (int c = 1; c < CC; c++) {
            if (lg[c] > mx) { mx = lg[c]; arg = c; }
        }
        float se = 0.0f;
#pragma unroll
        for (int c = 0; c < CC; c++) se += expf(lg[c] - mx);
        float lse = mx + logf(se);

        int g = b * SS + w0 + k;
        int lab = label_ids[g];
        lab = lab < 0 ? 0 : (lab > CC - 1 ? CC - 1 : lab);
        float valid = (len > 0) ? 1.0f : 0.0f;
        float nll = (lse - lg[lab]) * valid;

        pred_out[g] = (float)arg;

        float rn = rsum64(nll);
        float rc = rsum64(valid);
        if (t == 63) {
            nll_part[blockIdx.x] = rn;
            cnt_part[blockIdx.x] = rc;
        }
    }

    // ---- folded finalize: last block to arrive reduces the 512 partials ----
    __syncthreads();                    // partial stores issued by all lanes
    if (t == 0) {
        __threadfence();                // release our partial to device scope
        unsigned int prev = atomicAdd(done, 1u);
        lastflag = (prev == (unsigned int)(G2 - 1)) ? 1 : 0;
    }
    __syncthreads();
    if (lastflag) {
        __threadfence();                // acquire: see all blocks' partials
        // deterministic: fixed order regardless of arrival order
        float n = nll_part[t] + nll_part[t + 256];
        float c = cnt_part[t] + cnt_part[t + 256];
        n = rsum64(n);
        c = rsum64(c);
        if (lane == 63) { red[wave] = n; }
        __syncthreads();
        float cn0 = red[0], cn1 = red[1], cn2 = red[2], cn3 = red[3];
        __syncthreads();
        if (lane == 63) { red[wave] = c; }
        __syncthreads();
        if (t == 0) {
            float tn = cn0 + cn1 + cn2 + cn3;
            float tc = red[0] + red[1] + red[2] + red[3];
            out_loss[0] = tn / fmaxf(tc, 1.0f);
        }
    }
}

extern "C" void kernel_launch(void* const* d_in, const int* in_sizes, int n_in,
                              void* d_out, int out_size, void* d_ws, size_t ws_size,
                              hipStream_t stream) {
    const float* bert = (const float*)d_in[0]; // float32 [B,L,H]
    const float* Wm   = (const float*)d_in[1]; // float32 [H,C]
    const float* bias = (const float*)d_in[2]; // float32 [C]
    // d_in[3] = attention_mask (unused: prefix mask implied by ids_lens)
    const int* ids_lens  = (const int*)d_in[4];
    const int* label_ids = (const int*)d_in[5];
    // d_in[6] = label_mask (derived from ids_lens > 0)

    float* out = (float*)d_out;  // [0]=loss, [1..32768]=pred, float32

    float* WT_g     = (float*)d_ws;                    // [C][H]  27648 B
    float* RL       = WT_g + CC * HH;                  // [NROWS][RLS] 1.57 MB
    float* nll_part = RL + (size_t)NROWS * RLS;        // [G2]
    float* cnt_part = nll_part + G2;                   // [G2]
    unsigned int* done = (unsigned int*)(cnt_part + G2);

    wt_kernel<<<(HH * CC + 255) / 256, 256, 0, stream>>>(Wm, WT_g, done);
    row_gemm_kernel<<<G1, 256, 0, stream>>>(bert, WT_g, RL);
    pool_kernel<<<G2, 256, 0, stream>>>(RL, bias, ids_lens, label_ids,
                                        out + 1, nll_part, cnt_part, done, out);
}